// Round 6
// baseline (135.595 us; speedup 1.0000x reference)
//
#include <hip/hip_runtime.h>
#include <cstdint>

// B=16384 rows, K=2048 centers, D=128, T=1.0
// Outputs (flat, f32): out[B*D], center[K*D], label[B]
#define NB 16384
#define NK 2048
#define ND 128
#define MARGIN 0.10f
#define CAP 4096
#define XPITCH 132   // padded LDS x-row stride (floats)

typedef __attribute__((ext_vector_type(8))) short bf16x8;
typedef __attribute__((ext_vector_type(4))) float f32x4;
typedef unsigned long long u64;

__device__ __forceinline__ unsigned short f2bf(float f) {
    unsigned u = __float_as_uint(f);
    u += 0x7fffu + ((u >> 16) & 1u);          // round-to-nearest-even
    return (unsigned short)(u >> 16);
}

// Fixed-point encode of d2a for candidate storage: 16 bits, ulp 1/256,
// biased at 64, ROUND-UP (decode >= actual within range; clamps safe).
__device__ __forceinline__ unsigned enc16(float d2) {
    float d = fmaxf(d2, 0.f);
    if (d <= 64.f) return 0u;                  // 0 => always keep
    float t = (d - 64.f) * 256.f;
    unsigned q = (unsigned)t + 1u;             // trunc + 1 = round-up
    return q > 65535u ? 65535u : q;
}

// ---------------------------------------------------------------------------
// Prep (392 blocks):
//  [0,128)    cbf: center -> bf16 MFMA B-frag layout
//  [128,136)  c2 (chain identical to R1)
//  [136,392)  center passthrough copy (float4)
// ---------------------------------------------------------------------------
__global__ __launch_bounds__(256)
void prep(const float* __restrict__ c,
          unsigned short* __restrict__ cbf,
          float* __restrict__ c2,
          float* __restrict__ out_center) {
    const int bid = blockIdx.x;
    const int tid = threadIdx.x;
    if (bid < 128) {
        int t = bid * 256 + tid;              // 0..32767
        int lane = t & 63, s = (t >> 6) & 3, kt = t >> 8;
        int kc = kt * 16 + (lane & 15);
        int d0 = s * 32 + (lane >> 4) * 8;
        const float* src = c + (long)kc * ND + d0;
        unsigned short h[8];
#pragma unroll
        for (int j = 0; j < 8; ++j) h[j] = f2bf(src[j]);
        int4 pk;
        pk.x = h[0] | (h[1] << 16); pk.y = h[2] | (h[3] << 16);
        pk.z = h[4] | (h[5] << 16); pk.w = h[6] | (h[7] << 16);
        ((int4*)cbf)[t] = pk;
    } else if (bid < 136) {
        int k = (bid - 128) * 256 + tid;      // 0..2047
        const float4* row = (const float4*)(c + (long)k * ND);
        float s = 0.f;
#pragma unroll 8
        for (int i = 0; i < ND / 4; ++i) {
            float4 v = row[i];
            s += v.x * v.x + v.y * v.y + v.z * v.z + v.w * v.w;
        }
        c2[k] = s;
    } else {
        int i = (bid - 136) * 256 + tid;      // 0..K*D/4-1
        ((float4*)out_center)[i] = ((const float4*)c)[i];
    }
}

// ---------------------------------------------------------------------------
// Main: 1024 blocks x 256 threads. Block = 16 rows x ALL 2048 k -> block min
// IS the global min. Wave w sweeps k in [w*512, w*512+512) ONCE, collecting
// candidates with d2a <= running_min + MARGIN (superset of true candidates;
// running_min >= global_min always). Post-filter vs exact block min, then
// exact fp32 refine with the R1-identical chain. Direct out/label writes.
// ---------------------------------------------------------------------------
__global__ __launch_bounds__(256)
void kmeans_main(const float* __restrict__ x,
                 const float* __restrict__ center,
                 const unsigned short* __restrict__ cbf,
                 const float* __restrict__ c2,
                 float* __restrict__ out,
                 float* __restrict__ label_out) {
    __shared__ float xs[16 * XPITCH];          // 8.4 KB fp32 x rows
    __shared__ float x2s[16];
    __shared__ unsigned bmin[16];
    __shared__ u64 best[16];
    __shared__ unsigned buf[CAP];              // 16 KB candidates
    __shared__ unsigned cnt;

    const int tid  = threadIdx.x;
    const int lane = tid & 63;
    const int wave = __builtin_amdgcn_readfirstlane(tid >> 6);  // 0..3
    const long rb  = (long)blockIdx.x * 16;

    // ---- stage x rows -> LDS (coalesced, 2 float4/thread) ----
    {
        int r = tid >> 4, q = tid & 15;
        const float4* src = (const float4*)(x + (rb + r) * ND);
        float4 v0 = src[q], v1 = src[q + 16];
        float4* dst = (float4*)(xs + r * XPITCH);
        dst[q] = v0; dst[q + 16] = v1;
    }
    if (tid < 16) { bmin[tid] = 0x7f800000u; best[tid] = ~0ULL; }
    if (tid == 0) cnt = 0;
    __syncthreads();

    // ---- x2 per row: chain IDENTICAL to R1 (float2, 6-level butterfly) ----
    for (int i = 0; i < 4; ++i) {
        int r = wave * 4 + i;
        float2 v = *(const float2*)(xs + r * XPITCH + lane * 2);
        float s = v.x * v.x + v.y * v.y;
#pragma unroll
        for (int off = 32; off; off >>= 1) s += __shfl_xor(s, off, 64);
        if (lane == 0) x2s[r] = s;
    }
    __syncthreads();

    // ---- A-frags (one 16-row tile) into registers ----
    bf16x8 af[4];
#pragma unroll
    for (int s = 0; s < 4; ++s) {
        const float* p = xs + (lane & 15) * XPITCH + s * 32 + (lane >> 4) * 8;
        float4 u0 = ((const float4*)p)[0];
        float4 u1 = ((const float4*)p)[1];
        bf16x8 a;
        a[0] = (short)f2bf(u0.x); a[1] = (short)f2bf(u0.y);
        a[2] = (short)f2bf(u0.z); a[3] = (short)f2bf(u0.w);
        a[4] = (short)f2bf(u1.x); a[5] = (short)f2bf(u1.y);
        a[6] = (short)f2bf(u1.z); a[7] = (short)f2bf(u1.w);
        af[s] = a;
    }

    float x2p[4];
#pragma unroll
    for (int reg = 0; reg < 4; ++reg)
        x2p[reg] = x2s[(lane >> 4) * 4 + reg];

    const bf16x8* CF = (const bf16x8*)cbf;
    const int ktbase = wave * 32;              // wave's first 16-k tile

    float rmin[4];
#pragma unroll
    for (int reg = 0; reg < 4; ++reg) rmin[reg] = __builtin_inff();

    // one sweep over 32 k-tiles, candidate collection inline
#define CT_BODY(ct)                                                          \
    {                                                                        \
        const int kt = ktbase + (ct);                                        \
        bf16x8 bfr[4];                                                       \
        _Pragma("unroll")                                                    \
        for (int s = 0; s < 4; ++s) bfr[s] = CF[(kt * 4 + s) * 64 + lane];   \
        f32x4 acc = {0.f, 0.f, 0.f, 0.f};                                    \
        _Pragma("unroll")                                                    \
        for (int s = 0; s < 4; ++s)                                          \
            acc = __builtin_amdgcn_mfma_f32_16x16x32_bf16(af[s], bfr[s], acc, 0, 0, 0); \
        const float c2v = c2[kt * 16 + (lane & 15)];                         \
        const int col = kt * 16 + (lane & 15);                               \
        _Pragma("unroll")                                                    \
        for (int reg = 0; reg < 4; ++reg) {                                  \
            float d2 = fmaf(-2.f, acc[reg], x2p[reg] + c2v);                 \
            rmin[reg] = fminf(rmin[reg], d2);                                \
            if (d2 <= rmin[reg] + MARGIN) {                                  \
                unsigned rloc = (lane >> 4) * 4 + reg;                       \
                unsigned idx = atomicAdd(&cnt, 1u);                          \
                if (idx < CAP) {                                             \
                    buf[idx] = (enc16(d2) << 16) | (rloc << 11) | (unsigned)col; \
                } else {                                                     \
                    /* overflow fallback: exact refine NOW (R1 chain) */     \
                    const float* xr = xs + rloc * XPITCH;                    \
                    const float* cr = center + (long)col * ND;               \
                    float dot = 0.f;                                         \
                    _Pragma("unroll 8")                                      \
                    for (int d = 0; d < ND; ++d) dot = fmaf(xr[d], cr[d], dot); \
                    float t = x2s[rloc] + c2[col];                           \
                    float f = fmaxf(fmaf(-2.0f, dot, t), 0.0f);              \
                    float sq = __builtin_sqrtf(f);                           \
                    u64 key = ((u64)__float_as_uint(sq) << 32) | (unsigned)col; \
                    atomicMin(&best[rloc], key);                             \
                }                                                            \
            }                                                                \
        }                                                                    \
    }

    // first 4 tiles (running min is noisy -> collect freely)
    for (int ct = 0; ct < 4; ++ct) CT_BODY(ct)

    // tighten running min across the 16 col-lanes (same rows): kills most
    // later weak-records; rmin stays >= global min (safe).
#pragma unroll
    for (int reg = 0; reg < 4; ++reg) {
        float v = rmin[reg];
#pragma unroll
        for (int off = 1; off < 16; off <<= 1)
            v = fminf(v, __shfl_xor(v, off, 64));
        rmin[reg] = v;
    }

#pragma unroll 2
    for (int ct = 4; ct < 32; ++ct) CT_BODY(ct)
#undef CT_BODY

    // ---- exact block min per row ----
#pragma unroll
    for (int reg = 0; reg < 4; ++reg) {
        float v = rmin[reg];
#pragma unroll
        for (int off = 1; off < 16; off <<= 1)
            v = fminf(v, __shfl_xor(v, off, 64));
        if ((lane & 15) == 0)                  // d2a >= 0 -> uint order ok
            atomicMin(&bmin[(lane >> 4) * 4 + reg], __float_as_uint(v));
    }
    __syncthreads();

    // ---- post-filter + exact refine (fp32 chain IDENTICAL to R1) ----
    unsigned n = cnt; if (n > CAP) n = CAP;
    for (unsigned i = tid; i < n; i += 256) {
        unsigned e = buf[i];
        unsigned q = e >> 16;
        int rloc = (e >> 11) & 15, col = e & (NK - 1);
        float thr = __uint_as_float(bmin[rloc]) + MARGIN + 0.01f;
        float val = 64.f + (float)q * (1.f / 256.f);
        if (q != 0u && val > thr) continue;    // decode >= actual -> safe drop
        const float* xr = xs + rloc * XPITCH;
        const float* cr = center + (long)col * ND;
        float dot = 0.f;
#pragma unroll 8
        for (int d = 0; d < ND; ++d) dot = fmaf(xr[d], cr[d], dot);
        float t = x2s[rloc] + c2[col];
        float f = fmaxf(fmaf(-2.0f, dot, t), 0.0f);
        float s = __builtin_sqrtf(f);
        u64 key = ((u64)__float_as_uint(s) << 32) | (unsigned)col;
        atomicMin(&best[rloc], key);
    }
    __syncthreads();

    // ---- direct output: gather center[bk] per row + label ----
    for (int i = 0; i < 4; ++i) {
        int rloc = wave * 4 + i;
        int bk = (int)(best[rloc] & 0xffffffffULL);
        float2 cv = ((const float2*)(center + (long)bk * ND))[lane];
        ((float2*)(out + (rb + rloc) * ND))[lane] = cv;
        if (lane == 0) label_out[rb + rloc] = (float)bk;
    }
}

// ---------------------------------------------------------------------------
extern "C" void kernel_launch(void* const* d_in, const int* in_sizes, int n_in,
                              void* d_out, int out_size, void* d_ws, size_t ws_size,
                              hipStream_t stream) {
    const float* x      = (const float*)d_in[0];   // [B][D]
    const float* center = (const float*)d_in[1];   // [K][D]
    float* out = (float*)d_out;

    float* out_x      = out;                        // [B*D]
    float* out_center = out + (long)NB * ND;        // [K*D]
    float* out_label  = out_center + (long)NK * ND; // [B]

    // Workspace: cbf[K*D]u16 (0.5MB), c2[K]f32
    unsigned short* cbf = (unsigned short*)d_ws;
    float* c2 = (float*)(cbf + (size_t)NK * ND);

    prep<<<392, 256, 0, stream>>>(center, cbf, c2, out_center);
    kmeans_main<<<NB / 16, 256, 0, stream>>>(x, center, cbf, c2,
                                             out_x, out_label);
}